// Round 1
// baseline (2687.375 us; speedup 1.0000x reference)
//
#include <hip/hip_runtime.h>
#include <math.h>

typedef _Float16 f16x8 __attribute__((ext_vector_type(8)));
typedef _Float16 f16x4 __attribute__((ext_vector_type(4)));
typedef float    f32x4 __attribute__((ext_vector_type(4)));

// ---------------- conversion f32 -> f16 ----------------
__global__ __launch_bounds__(256) void k_f32_to_f16(const float* __restrict__ src,
                                                    _Float16* __restrict__ dst, int n4) {
  int i = blockIdx.x * 256 + threadIdx.x;
  int stride = gridDim.x * 256;
  for (; i < n4; i += stride) {
    float4 v = ((const float4*)src)[i];
    f16x4 o;
    o.x = (_Float16)v.x; o.y = (_Float16)v.y; o.z = (_Float16)v.z; o.w = (_Float16)v.w;
    ((f16x4*)dst)[i] = o;
  }
}

// ---------------- embedding + relu ----------------
// x rows are time-major: row r = t*32 + b
__global__ __launch_bounds__(256) void k_embed(const int* __restrict__ dec,
                                               const float* __restrict__ emb,
                                               float* __restrict__ xf,
                                               _Float16* __restrict__ xh) {
  int i = blockIdx.x * 256 + threadIdx.x;  // 524288 float4 units exactly
  int r = i >> 8;
  int c4 = i & 255;
  int b = r & 31, t = r >> 5;
  int tok = dec[b * 64 + t];
  float4 v = ((const float4*)(emb + (size_t)tok * 1024))[c4];
  v.x = fmaxf(v.x, 0.f); v.y = fmaxf(v.y, 0.f); v.z = fmaxf(v.z, 0.f); v.w = fmaxf(v.w, 0.f);
  ((float4*)(xf + (size_t)r * 1024))[c4] = v;
  f16x4 o;
  o.x = (_Float16)v.x; o.y = (_Float16)v.y; o.z = (_Float16)v.z; o.w = (_Float16)v.w;
  ((f16x4*)(xh + (size_t)r * 1024))[c4] = o;
}

// ---------------- state init ----------------
__global__ __launch_bounds__(256) void k_init(const float* __restrict__ h0, const float* __restrict__ c0,
                                              float* __restrict__ h, float* __restrict__ c,
                                              _Float16* __restrict__ hh) {
  int i = blockIdx.x * 256 + threadIdx.x;  // 65536
  float hv = h0[i];
  h[i] = hv; c[i] = c0[i]; hh[i] = (_Float16)hv;
}

// ---------------- final h/c copy ----------------
__global__ __launch_bounds__(256) void k_copy_hc(const float* __restrict__ h, const float* __restrict__ c,
                                                 float* __restrict__ oh, float* __restrict__ oc) {
  int i = blockIdx.x * 256 + threadIdx.x;  // 65536
  oh[i] = h[i]; oc[i] = c[i];
}

// ---------------- tiled MFMA GEMM: C[M,N] = A[M,1024] * B[N,1024]^T ----------------
// MODE 0: C row-major stride 8192 (gx precompute), bias = bias0[ng] + bias1[ng]
// MODE 1: logits: row rg=(t*32+b) remapped to (b*64+t), stride 32000, bias = bias0[ng]
template <int MODE>
__global__ __launch_bounds__(256) void k_gemm(const _Float16* __restrict__ A,
                                              const _Float16* __restrict__ Bm,
                                              const float* __restrict__ bias0,
                                              const float* __restrict__ bias1,
                                              float* __restrict__ C) {
  __shared__ _Float16 As[128 * 32];
  __shared__ _Float16 Bs[128 * 32];
  const int tid = threadIdx.x;
  const int lane = tid & 63;
  const int w = tid >> 6;
  const int wm = w >> 1, wn = w & 1;
  const _Float16* Ab = A + (size_t)blockIdx.y * 128 * 1024;
  const _Float16* Bb = Bm + (size_t)blockIdx.x * 128 * 1024;
  f32x4 acc[4][4] = {};
  for (int kc = 0; kc < 32; ++kc) {
#pragma unroll
    for (int ii = 0; ii < 2; ++ii) {
      int idx = tid + ii * 256;
      int row = idx >> 2, kb = idx & 3;
      int gofs = row * 1024 + kc * 32 + kb * 8;
      int sofs = row * 32 + ((kb ^ (row & 3)) * 8);
      *(f16x8*)(As + sofs) = *(const f16x8*)(Ab + gofs);
      *(f16x8*)(Bs + sofs) = *(const f16x8*)(Bb + gofs);
    }
    __syncthreads();
    const int kq = ((lane >> 4) ^ (lane & 3)) * 8;
    f16x8 af[4], bfv[4];
#pragma unroll
    for (int mf = 0; mf < 4; ++mf) {
      int row = wm * 64 + mf * 16 + (lane & 15);
      af[mf] = *(const f16x8*)(As + row * 32 + kq);
    }
#pragma unroll
    for (int nf = 0; nf < 4; ++nf) {
      int row = wn * 64 + nf * 16 + (lane & 15);
      bfv[nf] = *(const f16x8*)(Bs + row * 32 + kq);
    }
#pragma unroll
    for (int mf = 0; mf < 4; ++mf)
#pragma unroll
      for (int nf = 0; nf < 4; ++nf)
        acc[mf][nf] = __builtin_amdgcn_mfma_f32_16x16x32_f16(af[mf], bfv[nf], acc[mf][nf], 0, 0, 0);
    __syncthreads();
  }
  const int rl = (lane >> 4) * 4;
#pragma unroll
  for (int mf = 0; mf < 4; ++mf) {
#pragma unroll
    for (int nf = 0; nf < 4; ++nf) {
#pragma unroll
      for (int j = 0; j < 4; ++j) {
        int m = wm * 64 + mf * 16 + rl + j;
        int n = wn * 64 + nf * 16 + (lane & 15);
        int rg = blockIdx.y * 128 + m;
        int ng = blockIdx.x * 128 + n;
        float v = acc[mf][nf][j];
        if constexpr (MODE == 0) {
          C[(size_t)rg * 8192 + ng] = v + bias0[ng] + bias1[ng];
        } else {
          int tt = rg >> 5, b = rg & 31;
          C[(size_t)(b * 64 + tt) * 32000 + ng] = v + bias0[ng];
        }
      }
    }
  }
}

// ---------------- fused LSTM layer-step: gates GEMM (MFMA) + cell + residual ----------------
// Block covers 16 units (64 gate-cols = 4 gates x 16 units), all 32 batches. Grid = 64.
// gates_raw = A1 @ B1^T (+ A2 @ B2^T if nparts==2); full gates = raw + gx (x-part + biases).
__global__ __launch_bounds__(256) void k_lstm(const _Float16* __restrict__ A1,
                                              const _Float16* __restrict__ B1,
                                              const _Float16* __restrict__ A2,
                                              const _Float16* __restrict__ B2,
                                              int nparts,
                                              const float* __restrict__ gx,  // [32][*] slice, row stride 8192
                                              float* __restrict__ c_st,
                                              float* __restrict__ h_f,
                                              _Float16* __restrict__ h_h,
                                              const float* __restrict__ rin,
                                              float* __restrict__ rout,
                                              _Float16* __restrict__ rout_h) {
  __shared__ _Float16 As[32 * 32];
  __shared__ _Float16 Bs[64 * 32];
  __shared__ float gs[32][68];
  const int tid = threadIdx.x;
  const int lane = tid & 63;
  const int w = tid >> 6;
  const int u0 = blockIdx.x * 16;
  const int nk = nparts << 5;

  const int arow = tid >> 2, akb = tid & 3;  // A: 32 rows x 4 chunks (tid<128)
  const int brow = tid >> 2, bkb = tid & 3;  // B: 64 rows x 4 chunks (all 256)
  const size_t agofs = (size_t)arow * 1024 + (size_t)akb * 8;
  const size_t bgofs = (size_t)(((brow >> 4) << 10) + u0 + (brow & 15)) * 1024 + (size_t)bkb * 8;

  f16x8 pa, pb;
  {
    const _Float16* Bp = B1;
    pb = *(const f16x8*)(Bp + bgofs);
    if (tid < 128) pa = *(const f16x8*)(A1 + agofs);
  }
  f32x4 acc[2] = {};
  for (int kci = 0; kci < nk; ++kci) {
    *(f16x8*)(Bs + brow * 32 + ((bkb ^ (brow & 3)) * 8)) = pb;
    if (tid < 128) *(f16x8*)(As + arow * 32 + ((akb ^ (arow & 3)) * 8)) = pa;
    __syncthreads();
    int knx = kci + 1;
    if (knx < nk) {
      const _Float16* Ap = (knx >> 5) ? A2 : A1;
      const _Float16* Bp = (knx >> 5) ? B2 : B1;
      pb = *(const f16x8*)(Bp + bgofs + (size_t)(knx & 31) * 32);
      if (tid < 128) pa = *(const f16x8*)(Ap + agofs + (size_t)(knx & 31) * 32);
    }
    const int kq = ((lane >> 4) ^ (lane & 3)) * 8;
    f16x8 af0 = *(const f16x8*)(As + (lane & 15) * 32 + kq);
    f16x8 af1 = *(const f16x8*)(As + (16 + (lane & 15)) * 32 + kq);
    f16x8 bv = *(const f16x8*)(Bs + (w * 16 + (lane & 15)) * 32 + kq);
    acc[0] = __builtin_amdgcn_mfma_f32_16x16x32_f16(af0, bv, acc[0], 0, 0, 0);
    acc[1] = __builtin_amdgcn_mfma_f32_16x16x32_f16(af1, bv, acc[1], 0, 0, 0);
    __syncthreads();
  }
  const int rl = (lane >> 4) * 4;
#pragma unroll
  for (int mf = 0; mf < 2; ++mf)
#pragma unroll
    for (int j = 0; j < 4; ++j)
      gs[mf * 16 + rl + j][w * 16 + (lane & 15)] = acc[mf][j];
  __syncthreads();
#pragma unroll
  for (int ii = 0; ii < 2; ++ii) {
    int idx = tid + ii * 256;
    int b = idx >> 4, ul = idx & 15;
    int u = u0 + ul;
    const float* gxr = gx + b * 8192;
    float ig = gs[b][ul]      + gxr[u];
    float fg = gs[b][16 + ul] + gxr[1024 + u];
    float gg = gs[b][32 + ul] + gxr[2048 + u];
    float og = gs[b][48 + ul] + gxr[3072 + u];
    float cp = c_st[b * 1024 + u];
    float si = 1.f / (1.f + expf(-ig));
    float sf = 1.f / (1.f + expf(-fg));
    float so = 1.f / (1.f + expf(-og));
    float ci = sf * cp + si * tanhf(gg);
    float hi = so * tanhf(ci);
    c_st[b * 1024 + u] = ci;
    h_f[b * 1024 + u] = hi;
    h_h[b * 1024 + u] = (_Float16)hi;
    float ro = hi + rin[b * 1024 + u];
    rout[b * 1024 + u] = ro;
    if (rout_h) rout_h[b * 1024 + u] = (_Float16)ro;
  }
}

// ---------------- batched dot-attention + softmax ----------------
// block: (b, group of 8 t). scores[tt][s] = <enc[b,s,:], outs[t0+tt, b, :]>, softmax over s.
__global__ __launch_bounds__(256) void k_attn(const float* __restrict__ outs,
                                              const float* __restrict__ enc,
                                              float* __restrict__ att) {
  __shared__ float o_s[8][1024];
  __shared__ float sc[8][128];
  const int tid = threadIdx.x;
  const int lane = tid & 63;
  const int w = tid >> 6;
  const int b = blockIdx.x >> 3;
  const int t0 = (blockIdx.x & 7) * 8;
#pragma unroll
  for (int ii = 0; ii < 8; ++ii) {
    int idx = tid + ii * 256;
    int tt = idx >> 8, c4 = idx & 255;
    ((float4*)&o_s[tt][0])[c4] =
        *(const float4*)(outs + (size_t)((t0 + tt) * 32 + b) * 1024 + (size_t)c4 * 4);
  }
  __syncthreads();
  for (int si = 0; si < 32; ++si) {
    int s = w * 32 + si;
    float av[8] = {0, 0, 0, 0, 0, 0, 0, 0};
    const float* er = enc + (size_t)(b * 128 + s) * 1024;
#pragma unroll
    for (int i = 0; i < 4; ++i) {
      int k = i * 256 + lane * 4;
      float4 e = *(const float4*)(er + k);
#pragma unroll
      for (int tt = 0; tt < 8; ++tt) {
        float4 o = *(const float4*)&o_s[tt][k];
        av[tt] += e.x * o.x + e.y * o.y + e.z * o.z + e.w * o.w;
      }
    }
#pragma unroll
    for (int tt = 0; tt < 8; ++tt) {
      float v = av[tt];
#pragma unroll
      for (int off = 32; off > 0; off >>= 1) v += __shfl_down(v, off);
      if (lane == 0) sc[tt][s] = v;
    }
  }
  __syncthreads();
#pragma unroll
  for (int pp = 0; pp < 2; ++pp) {
    int tt = w + pp * 4;
    float a = sc[tt][lane], b2 = sc[tt][64 + lane];
    float m = fmaxf(a, b2);
#pragma unroll
    for (int off = 32; off > 0; off >>= 1) m = fmaxf(m, __shfl_xor(m, off));
    float e0 = expf(a - m), e1 = expf(b2 - m);
    float ss = e0 + e1;
#pragma unroll
    for (int off = 32; off > 0; off >>= 1) ss += __shfl_xor(ss, off);
    float r = 1.f / ss;
    att[(size_t)b * 8192 + (size_t)lane * 64 + t0 + tt] = e0 * r;
    att[(size_t)b * 8192 + (size_t)(64 + lane) * 64 + t0 + tt] = e1 * r;
  }
}

extern "C" void kernel_launch(void* const* d_in, const int* in_sizes, int n_in,
                              void* d_out, int out_size, void* d_ws, size_t ws_size,
                              hipStream_t stream) {
  const int*   dec   = (const int*)d_in[0];
  const float* h0    = (const float*)d_in[1];
  const float* c0    = (const float*)d_in[2];
  const float* enc   = (const float*)d_in[3];
  const float* emb   = (const float*)d_in[4];
  const float* W_ih  = (const float*)d_in[5];
  const float* W_hh  = (const float*)d_in[6];
  const float* b_ih  = (const float*)d_in[7];
  const float* b_hh  = (const float*)d_in[8];
  const float* cls_W = (const float*)d_in[9];
  const float* cls_b = (const float*)d_in[10];
  float* out = (float*)d_out;
  char* ws = (char*)d_ws;

  float*    x_f    = (float*)(ws + 0);                // [2048][1024] f32
  _Float16* x_h    = (_Float16*)(ws + 8388608);       // [2048][1024] f16
  _Float16* Wih_h  = (_Float16*)(ws + 12582912);      // [8192][1024] f16
  _Float16* Whh_h  = (_Float16*)(ws + 29360128);      // [8192][1024] f16
  _Float16* clsW_h = (_Float16*)(ws + 46137344);      // [32000][1024] f16
  float*    gx     = (float*)(ws + 111673344);        // [2048][8192] f32
  float*    outs_f = (float*)(ws + 178782208);        // [2048][1024] f32
  _Float16* outs_h = (_Float16*)(ws + 187170816);     // [2048][1024] f16
  float*    h_f    = (float*)(ws + 191365120);        // [2][32][1024] f32
  float*    c_f    = (float*)(ws + 191627264);        // [2][32][1024] f32
  _Float16* hb0    = (_Float16*)(ws + 191889408);     // ping [2][32][1024] f16
  _Float16* hb1    = (_Float16*)(ws + 192020480);     // pong
  float*    inp1   = (float*)(ws + 192151552);        // [32][1024] f32

  k_f32_to_f16<<<2048, 256, 0, stream>>>(W_ih, Wih_h, 2097152);
  k_f32_to_f16<<<2048, 256, 0, stream>>>(W_hh, Whh_h, 2097152);
  k_f32_to_f16<<<4096, 256, 0, stream>>>(cls_W, clsW_h, 8192000);
  k_embed<<<2048, 256, 0, stream>>>(dec, emb, x_f, x_h);
  k_init<<<256, 256, 0, stream>>>(h0, c0, h_f, c_f, hb0);
  // gx[r][0:4096]   = x@W_ih0^T + b_ih0 + b_hh0
  // gx[r][4096:8192]= x@W_ih1^T + b_ih1 + b_hh1   (b_ih/b_hh are [2,4096] contiguous)
  k_gemm<0><<<dim3(64, 16), 256, 0, stream>>>(x_h, Wih_h, b_ih, b_hh, gx);

  _Float16* hc = hb0;
  _Float16* hn = hb1;
  for (int t = 0; t < 64; ++t) {
    // layer 0: gates = h0 @ W_hh0^T + gx0[t]
    k_lstm<<<64, 256, 0, stream>>>(hc, Whh_h, (const _Float16*)nullptr, (const _Float16*)nullptr, 1,
                                   gx + (size_t)t * 32 * 8192,
                                   c_f, h_f, hn,
                                   x_f + (size_t)t * 32 * 1024, inp1, (_Float16*)nullptr);
    // layer 1: gates = hi0 @ W_ih1^T + h1 @ W_hh1^T + gx1[t]
    k_lstm<<<64, 256, 0, stream>>>(hn, Wih_h + (size_t)4096 * 1024,
                                   hc + 32 * 1024, Whh_h + (size_t)4096 * 1024, 2,
                                   gx + (size_t)t * 32 * 8192 + 4096,
                                   c_f + 32768, h_f + 32768, hn + 32 * 1024,
                                   inp1, outs_f + (size_t)t * 32 * 1024, outs_h + (size_t)t * 32 * 1024);
    _Float16* tmp = hc; hc = hn; hn = tmp;
  }
  k_attn<<<256, 256, 0, stream>>>(outs_f, enc, out + (size_t)65667072);
  k_gemm<1><<<dim3(250, 16), 256, 0, stream>>>(outs_h, clsW_h, cls_b, (const float*)nullptr, out);
  k_copy_hc<<<256, 256, 0, stream>>>(h_f, c_f, out + (size_t)65536000, out + (size_t)65601536);
}

// Round 2
// 1351.035 us; speedup vs baseline: 1.9891x; 1.9891x over previous
//
#include <hip/hip_runtime.h>
#include <math.h>

typedef _Float16 f16x8 __attribute__((ext_vector_type(8)));
typedef _Float16 f16x4 __attribute__((ext_vector_type(4)));
typedef float    f32x4 __attribute__((ext_vector_type(4)));

// ---------------- conversion f32 -> f16 ----------------
__global__ __launch_bounds__(256) void k_f32_to_f16(const float* __restrict__ src,
                                                    _Float16* __restrict__ dst, int n4) {
  int i = blockIdx.x * 256 + threadIdx.x;
  int stride = gridDim.x * 256;
  for (; i < n4; i += stride) {
    float4 v = ((const float4*)src)[i];
    f16x4 o;
    o.x = (_Float16)v.x; o.y = (_Float16)v.y; o.z = (_Float16)v.z; o.w = (_Float16)v.w;
    ((f16x4*)dst)[i] = o;
  }
}

// ---------------- embedding + relu ----------------
// x rows are time-major: row r = t*32 + b
__global__ __launch_bounds__(256) void k_embed(const int* __restrict__ dec,
                                               const float* __restrict__ emb,
                                               float* __restrict__ xf,
                                               _Float16* __restrict__ xh) {
  int i = blockIdx.x * 256 + threadIdx.x;  // 524288 float4 units exactly
  int r = i >> 8;
  int c4 = i & 255;
  int b = r & 31, t = r >> 5;
  int tok = dec[b * 64 + t];
  float4 v = ((const float4*)(emb + (size_t)tok * 1024))[c4];
  v.x = fmaxf(v.x, 0.f); v.y = fmaxf(v.y, 0.f); v.z = fmaxf(v.z, 0.f); v.w = fmaxf(v.w, 0.f);
  ((float4*)(xf + (size_t)r * 1024))[c4] = v;
  f16x4 o;
  o.x = (_Float16)v.x; o.y = (_Float16)v.y; o.z = (_Float16)v.z; o.w = (_Float16)v.w;
  ((f16x4*)(xh + (size_t)r * 1024))[c4] = o;
}

// ---------------- state init ----------------
// h0 input layout [2][32][1024]; write f32 state + f16 ping-pong slots ("phase -1" = buf1)
__global__ __launch_bounds__(256) void k_init(const float* __restrict__ h0, const float* __restrict__ c0,
                                              float* __restrict__ h, float* __restrict__ c,
                                              _Float16* __restrict__ h0B, _Float16* __restrict__ h1B) {
  int i = blockIdx.x * 256 + threadIdx.x;  // 65536
  float hv = h0[i];
  h[i] = hv; c[i] = c0[i];
  if (i < 32768) h0B[i] = (_Float16)hv;
  else           h1B[i - 32768] = (_Float16)hv;
}

// ---------------- final h/c copy ----------------
__global__ __launch_bounds__(256) void k_copy_hc(const float* __restrict__ h, const float* __restrict__ c,
                                                 float* __restrict__ oh, float* __restrict__ oc) {
  int i = blockIdx.x * 256 + threadIdx.x;  // 65536
  oh[i] = h[i]; oc[i] = c[i];
}

// ---------------- tiled MFMA GEMM: C[M,N] = A[M,1024] * B[N,1024]^T ----------------
// MODE 0: C row-major stride 8192 (gx precompute), bias = bias0[ng] + bias1[ng]
// MODE 1: logits: row rg=(t*32+b) remapped to (b*64+t), stride 32000, bias = bias0[ng]
template <int MODE>
__global__ __launch_bounds__(256) void k_gemm(const _Float16* __restrict__ A,
                                              const _Float16* __restrict__ Bm,
                                              const float* __restrict__ bias0,
                                              const float* __restrict__ bias1,
                                              float* __restrict__ C) {
  __shared__ _Float16 As[128 * 32];
  __shared__ _Float16 Bs[128 * 32];
  const int tid = threadIdx.x;
  const int lane = tid & 63;
  const int w = tid >> 6;
  const int wm = w >> 1, wn = w & 1;
  const _Float16* Ab = A + (size_t)blockIdx.y * 128 * 1024;
  const _Float16* Bb = Bm + (size_t)blockIdx.x * 128 * 1024;
  f32x4 acc[4][4] = {};
  for (int kc = 0; kc < 32; ++kc) {
#pragma unroll
    for (int ii = 0; ii < 2; ++ii) {
      int idx = tid + ii * 256;
      int row = idx >> 2, kb = idx & 3;
      int gofs = row * 1024 + kc * 32 + kb * 8;
      int sofs = row * 32 + ((kb ^ (row & 3)) * 8);
      *(f16x8*)(As + sofs) = *(const f16x8*)(Ab + gofs);
      *(f16x8*)(Bs + sofs) = *(const f16x8*)(Bb + gofs);
    }
    __syncthreads();
    const int kq = ((lane >> 4) ^ (lane & 3)) * 8;
    f16x8 af[4], bfv[4];
#pragma unroll
    for (int mf = 0; mf < 4; ++mf) {
      int row = wm * 64 + mf * 16 + (lane & 15);
      af[mf] = *(const f16x8*)(As + row * 32 + kq);
    }
#pragma unroll
    for (int nf = 0; nf < 4; ++nf) {
      int row = wn * 64 + nf * 16 + (lane & 15);
      bfv[nf] = *(const f16x8*)(Bs + row * 32 + kq);
    }
#pragma unroll
    for (int mf = 0; mf < 4; ++mf)
#pragma unroll
      for (int nf = 0; nf < 4; ++nf)
        acc[mf][nf] = __builtin_amdgcn_mfma_f32_16x16x32_f16(af[mf], bfv[nf], acc[mf][nf], 0, 0, 0);
    __syncthreads();
  }
  const int rl = (lane >> 4) * 4;
#pragma unroll
  for (int mf = 0; mf < 4; ++mf) {
#pragma unroll
    for (int nf = 0; nf < 4; ++nf) {
#pragma unroll
      for (int j = 0; j < 4; ++j) {
        int m = wm * 64 + mf * 16 + rl + j;
        int n = wn * 64 + nf * 16 + (lane & 15);
        int rg = blockIdx.y * 128 + m;
        int ng = blockIdx.x * 128 + n;
        float v = acc[mf][nf][j];
        if constexpr (MODE == 0) {
          C[(size_t)rg * 8192 + ng] = v + bias0[ng] + bias1[ng];
        } else {
          int tt = rg >> 5, b = rg & 31;
          C[(size_t)(b * 64 + tt) * 32000 + ng] = v + bias0[ng];
        }
      }
    }
  }
}

// ---------------- pipelined LSTM phase kernel ----------------
// Phase p: blocks 0..63 compute layer0 of step t=p (skip if p==64);
//          blocks 64..127 compute layer1 of step t=p-1 (skip if p==0).
// Layer0 gates = h0(t-1) @ Whh0^T + gx0[t]           (gx0 = x@Wih0^T + biases)
// Layer1 gates = h0'(t) @ Wih1^T + h1(t-1) @ Whh1^T + gx1[t]  (gx1 = x@Wih1^T + biases;
//                distributivity: (h0'+x)@Wih1 = h0'@Wih1 + x@Wih1)
// Block = 16 units; wave w = gate w (rows w*1024+u0..+16 of the weight matrix).
// A (the h vectors, [32 x K]) staged LDS in 256-K chunks; B (weights) read direct from L2.
__global__ __launch_bounds__(256) void k_phase(int p,
    const _Float16* __restrict__ Wih_h, const _Float16* __restrict__ Whh_h,
    const float* __restrict__ gx, const float* __restrict__ x_f,
    float* __restrict__ c_f, float* __restrict__ h_f,
    _Float16* __restrict__ h0A, _Float16* __restrict__ h0B,
    _Float16* __restrict__ h1A, _Float16* __restrict__ h1B,
    float* __restrict__ ipfA, float* __restrict__ ipfB,
    float* __restrict__ outs_f, _Float16* __restrict__ outs_h) {
  const int role = blockIdx.x >> 6;
  if (role == 0 && p == 64) return;
  if (role == 1 && p == 0) return;
  const int jb = blockIdx.x & 63;
  const int u0 = jb * 16;
  const int t = (role == 0) ? p : p - 1;
  const int tid = threadIdx.x;
  const int lane = tid & 63;
  const int w = tid >> 6;
  const int col = lane & 15;
  const int kq = (lane >> 4) * 8;

  // ping-pong selection: state(t) lives in buf[t&1]; initial state in buf1.
  const _Float16 *h0r, *h1r;
  _Float16 *h0w, *h1w;
  const float* ipfr; float* ipfw;
  if (p & 1) { h0r = h0A; h0w = h0B; ipfr = ipfA; ipfw = ipfB; h1r = h1B; h1w = h1A; }
  else       { h0r = h0B; h0w = h0A; ipfr = ipfB; ipfw = ipfA; h1r = h1A; h1w = h1B; }

  __shared__ _Float16 As[2][32 * 264];  // 264 = 256 + 8 pad (f16) -> 528B row stride, 2-way banks
  __shared__ float gs[32][66];

  // B per-lane base pointers (row = gate-col = w*1024 + u0 + col)
  const _Float16* bp0;
  const _Float16* bp1 = nullptr;
  if (role == 0) {
    bp0 = Whh_h + (size_t)(w * 1024 + u0 + col) * 1024 + kq;
  } else {
    bp0 = Wih_h + (size_t)(4096 + w * 1024 + u0 + col) * 1024 + kq;
    bp1 = Whh_h + (size_t)(4096 + w * 1024 + u0 + col) * 1024 + kq;
  }

  const int NC = role ? 8 : 4;

  auto stage_issue = [&](int c, f16x8* regs) {
#pragma unroll
    for (int q = 0; q < 4; ++q) {
      int id = q * 256 + tid;
      int row = id >> 5, k8 = id & 31;
      int k = c * 256 + k8 * 8;
      const _Float16* s = (k < 1024) ? (h0r + row * 1024 + k)
                                     : (h1r + row * 1024 + (k - 1024));
      regs[q] = *(const f16x8*)s;
    }
  };
  auto stage_write = [&](int c, const f16x8* regs) {
#pragma unroll
    for (int q = 0; q < 4; ++q) {
      int id = q * 256 + tid;
      int row = id >> 5, k8 = id & 31;
      *(f16x8*)(&As[c & 1][row * 264 + k8 * 8]) = regs[q];
    }
  };

  f32x4 acc0 = {}, acc1 = {};
  f16x8 sreg[4];
  stage_issue(0, sreg);
  stage_write(0, sreg);
  __syncthreads();
  for (int c = 0; c < NC; ++c) {
    // weight fragments for this chunk (direct from global/L2)
    f16x8 bf[8];
#pragma unroll
    for (int kk = 0; kk < 8; ++kk) {
      int kc = c * 8 + kk;
      const _Float16* bsrc = (kc >= 32) ? (bp1 + (size_t)(kc - 32) * 32)
                                        : (bp0 + (size_t)kc * 32);
      bf[kk] = *(const f16x8*)bsrc;
    }
    if (c + 1 < NC) stage_issue(c + 1, sreg);
#pragma unroll
    for (int kk = 0; kk < 8; ++kk) {
      f16x8 a0 = *(const f16x8*)(&As[c & 1][(col) * 264 + kk * 32 + kq]);
      f16x8 a1 = *(const f16x8*)(&As[c & 1][(16 + col) * 264 + kk * 32 + kq]);
      acc0 = __builtin_amdgcn_mfma_f32_16x16x32_f16(a0, bf[kk], acc0, 0, 0, 0);
      acc1 = __builtin_amdgcn_mfma_f32_16x16x32_f16(a1, bf[kk], acc1, 0, 0, 0);
    }
    if (c + 1 < NC) stage_write(c + 1, sreg);
    __syncthreads();
  }

  // exchange gate tiles: gs[batch][gate*16 + unit]
  const int rl = (lane >> 4) * 4;
#pragma unroll
  for (int j = 0; j < 4; ++j) {
    gs[rl + j][w * 16 + col] = acc0[j];
    gs[16 + rl + j][w * 16 + col] = acc1[j];
  }
  __syncthreads();

  // fused LSTM cell + residual for this block's 16 units, all 32 batches
  float* cst = c_f + role * 32768;
  float* hst = h_f + role * 32768;
  const float* gxbase = gx + (role ? 4096 : 0);
#pragma unroll
  for (int ii = 0; ii < 2; ++ii) {
    int idx = tid + ii * 256;
    int b = idx >> 4, ul = idx & 15;
    int u = u0 + ul;
    const float* gxr = gxbase + (size_t)(t * 32 + b) * 8192;
    float ig = gs[b][ul]      + gxr[u];
    float fg = gs[b][16 + ul] + gxr[1024 + u];
    float gg = gs[b][32 + ul] + gxr[2048 + u];
    float og = gs[b][48 + ul] + gxr[3072 + u];
    float cp = cst[b * 1024 + u];
    float si = 1.f / (1.f + expf(-ig));
    float sf = 1.f / (1.f + expf(-fg));
    float so = 1.f / (1.f + expf(-og));
    float ci = sf * cp + si * tanhf(gg);
    float hi = so * tanhf(ci);
    cst[b * 1024 + u] = ci;
    hst[b * 1024 + u] = hi;
    if (role == 0) {
      h0w[b * 1024 + u] = (_Float16)hi;
      float ip = hi + x_f[(size_t)(t * 32 + b) * 1024 + u];
      ipfw[b * 1024 + u] = ip;
    } else {
      h1w[b * 1024 + u] = (_Float16)hi;
      float ro = hi + ipfr[b * 1024 + u];
      outs_f[(size_t)(t * 32 + b) * 1024 + u] = ro;
      outs_h[(size_t)(t * 32 + b) * 1024 + u] = (_Float16)ro;
    }
  }
}

// ---------------- batched dot-attention + softmax ----------------
__global__ __launch_bounds__(256) void k_attn(const float* __restrict__ outs,
                                              const float* __restrict__ enc,
                                              float* __restrict__ att) {
  __shared__ float o_s[8][1024];
  __shared__ float sc[8][128];
  const int tid = threadIdx.x;
  const int lane = tid & 63;
  const int w = tid >> 6;
  const int b = blockIdx.x >> 3;
  const int t0 = (blockIdx.x & 7) * 8;
#pragma unroll
  for (int ii = 0; ii < 8; ++ii) {
    int idx = tid + ii * 256;
    int tt = idx >> 8, c4 = idx & 255;
    ((float4*)&o_s[tt][0])[c4] =
        *(const float4*)(outs + (size_t)((t0 + tt) * 32 + b) * 1024 + (size_t)c4 * 4);
  }
  __syncthreads();
  for (int si = 0; si < 32; ++si) {
    int s = w * 32 + si;
    float av[8] = {0, 0, 0, 0, 0, 0, 0, 0};
    const float* er = enc + (size_t)(b * 128 + s) * 1024;
#pragma unroll
    for (int i = 0; i < 4; ++i) {
      int k = i * 256 + lane * 4;
      float4 e = *(const float4*)(er + k);
#pragma unroll
      for (int tt = 0; tt < 8; ++tt) {
        float4 o = *(const float4*)&o_s[tt][k];
        av[tt] += e.x * o.x + e.y * o.y + e.z * o.z + e.w * o.w;
      }
    }
#pragma unroll
    for (int tt = 0; tt < 8; ++tt) {
      float v = av[tt];
#pragma unroll
      for (int off = 32; off > 0; off >>= 1) v += __shfl_down(v, off);
      if (lane == 0) sc[tt][s] = v;
    }
  }
  __syncthreads();
#pragma unroll
  for (int pp = 0; pp < 2; ++pp) {
    int tt = w + pp * 4;
    float a = sc[tt][lane], b2 = sc[tt][64 + lane];
    float m = fmaxf(a, b2);
#pragma unroll
    for (int off = 32; off > 0; off >>= 1) m = fmaxf(m, __shfl_xor(m, off));
    float e0 = expf(a - m), e1 = expf(b2 - m);
    float ss = e0 + e1;
#pragma unroll
    for (int off = 32; off > 0; off >>= 1) ss += __shfl_xor(ss, off);
    float r = 1.f / ss;
    att[(size_t)b * 8192 + (size_t)lane * 64 + t0 + tt] = e0 * r;
    att[(size_t)b * 8192 + (size_t)(64 + lane) * 64 + t0 + tt] = e1 * r;
  }
}

extern "C" void kernel_launch(void* const* d_in, const int* in_sizes, int n_in,
                              void* d_out, int out_size, void* d_ws, size_t ws_size,
                              hipStream_t stream) {
  const int*   dec   = (const int*)d_in[0];
  const float* h0    = (const float*)d_in[1];
  const float* c0    = (const float*)d_in[2];
  const float* enc   = (const float*)d_in[3];
  const float* emb   = (const float*)d_in[4];
  const float* W_ih  = (const float*)d_in[5];
  const float* W_hh  = (const float*)d_in[6];
  const float* b_ih  = (const float*)d_in[7];
  const float* b_hh  = (const float*)d_in[8];
  const float* cls_W = (const float*)d_in[9];
  const float* cls_b = (const float*)d_in[10];
  float* out = (float*)d_out;
  char* ws = (char*)d_ws;

  float*    x_f    = (float*)(ws + 0);                // [2048][1024] f32
  _Float16* x_h    = (_Float16*)(ws + 8388608);       // [2048][1024] f16 (dead after gx gemm)
  float*    ipfA   = (float*)(ws + 8388608);          // reuses x_h region (safe: stream-ordered)
  float*    ipfB   = (float*)(ws + 8519680);
  _Float16* Wih_h  = (_Float16*)(ws + 12582912);      // [8192][1024] f16
  _Float16* Whh_h  = (_Float16*)(ws + 29360128);      // [8192][1024] f16
  _Float16* clsW_h = (_Float16*)(ws + 46137344);      // [32000][1024] f16
  float*    gx     = (float*)(ws + 111673344);        // [2048][8192] f32
  float*    outs_f = (float*)(ws + 178782208);        // [2048][1024] f32
  _Float16* outs_h = (_Float16*)(ws + 187170816);     // [2048][1024] f16
  float*    h_f    = (float*)(ws + 191365120);        // [2][32][1024] f32
  float*    c_f    = (float*)(ws + 191627264);        // [2][32][1024] f32
  _Float16* h0A    = (_Float16*)(ws + 191889408);     // [32][1024] f16
  _Float16* h0B    = (_Float16*)(ws + 191954944);
  _Float16* h1A    = (_Float16*)(ws + 192020480);
  _Float16* h1B    = (_Float16*)(ws + 192086016);

  k_f32_to_f16<<<2048, 256, 0, stream>>>(W_ih, Wih_h, 2097152);
  k_f32_to_f16<<<2048, 256, 0, stream>>>(W_hh, Whh_h, 2097152);
  k_f32_to_f16<<<4096, 256, 0, stream>>>(cls_W, clsW_h, 8192000);
  k_embed<<<2048, 256, 0, stream>>>(dec, emb, x_f, x_h);
  k_init<<<256, 256, 0, stream>>>(h0, c0, h_f, c_f, h0B, h1B);
  // gx[r][0:4096]   = x@W_ih0^T + b_ih0 + b_hh0
  // gx[r][4096:8192]= x@W_ih1^T + b_ih1 + b_hh1
  k_gemm<0><<<dim3(64, 16), 256, 0, stream>>>(x_h, Wih_h, b_ih, b_hh, gx);

  for (int p = 0; p <= 64; ++p) {
    k_phase<<<128, 256, 0, stream>>>(p, Wih_h, Whh_h, gx, x_f, c_f, h_f,
                                     h0A, h0B, h1A, h1B, ipfA, ipfB, outs_f, outs_h);
  }

  k_attn<<<256, 256, 0, stream>>>(outs_f, enc, out + (size_t)65667072);
  k_gemm<1><<<dim3(250, 16), 256, 0, stream>>>(outs_h, clsW_h, cls_b, (const float*)nullptr, out);
  k_copy_hc<<<256, 256, 0, stream>>>(h_f, c_f, out + (size_t)65536000, out + (size_t)65601536);
}